// Round 3
// baseline (360.573 us; speedup 1.0000x reference)
//
#include <hip/hip_runtime.h>
#include <stdint.h>

#define D_DIM 1024
#define N_DIM 65536
#define BIN   16
#define Q_DIM 2048
#define K_DIM 3

#define NBLK  256          // one block per CU
#define TPB   1024
#define SUBW  32           // n-columns per load subtile (128 KB f32 per CU)
#define NSUB  8            // 8 subtiles -> 256 n per block
#define MACW  64           // n-columns per compute macro-tile (= 2 subtiles)
#define NMAC  4
#define LDS_BYTES (D_DIM * 128)   // bf16 table: 1024 rows x 64 cols = 131072 B

// round-to-nearest-even f32 -> bf16 (positive normal probs)
__device__ __forceinline__ uint32_t f2bf(float f) {
    uint32_t u = __float_as_uint(f);
    return (u + 0x7fffu + ((u >> 16) & 1u)) >> 16;
}

// qword-slot swizzle key for table row d: spreads banks for both the
// (g-structured) writes and the (random-d) reads.
__device__ __forceinline__ int fswz(int d) {
    return (d & 15) ^ (((d >> 4) & 1) << 3);
}

// issue 16 float2 loads (bins 0..15 of group g, columns col0+np*2 .. +1)
__device__ __forceinline__ void issue_loads(const float* __restrict__ W,
                                            float2* e, int g, int np, int col0) {
    const float2* wp = (const float2*)(W + (size_t)(g * BIN) * N_DIM + col0 + np * 2);
#pragma unroll
    for (int b = 0; b < BIN; ++b) e[b] = wp[(size_t)b * (N_DIM / 2)];
}

// exp-normalize the 16 bins x 2 cols in e[], pack bf16x2, store to table.
// sub in {0,1}: which 32-col half of the 64-col macro tile.
__device__ __forceinline__ void normalize_store(char* smem, float2* e,
                                                int g, int np, int sub) {
    float sx = 0.f, sy = 0.f;
#pragma unroll
    for (int b = 0; b < BIN; ++b) {
        e[b].x = __expf(e[b].x);
        e[b].y = __expf(e[b].y);
        sx += e[b].x; sy += e[b].y;
    }
    const float rx = __builtin_amdgcn_rcpf(sx);
    const float ry = __builtin_amdgcn_rcpf(sy);
    const int qw = sub * 8 + (np >> 1);   // qword slot 0..15 within row
    const int p  = (np & 1) << 2;         // dword parity (byte offset)
#pragma unroll
    for (int b = 0; b < BIN; ++b) {
        const int d = g * BIN + b;
        const uint32_t v = f2bf(e[b].x * rx) | (f2bf(e[b].y * ry) << 16);
        *(uint32_t*)(smem + (d << 7) + ((qw ^ fswz(d)) << 3) + p) = v;
    }
}

template<bool ATOMIC>
__global__ __launch_bounds__(TPB, 4) void rap_main(const float* __restrict__ W,
                                                   const int* __restrict__ qidx,
                                                   float* __restrict__ outp) {
    extern __shared__ char smem[];
    const int tid = threadIdx.x;
    const int bid = blockIdx.x;

    // ---- per-thread query constants (2 queries/thread) ----
    const int q0 = tid * 2;
    int baseb[2][K_DIM];   // d*128 : byte base of LDS row
    int swzb[2][K_DIM];    // fswz(d)*8 : qword XOR swizzle in bytes
#pragma unroll
    for (int qq = 0; qq < 2; ++qq) {
#pragma unroll
        for (int k = 0; k < K_DIM; ++k) {
            const int d = qidx[(q0 + qq) * K_DIM + k];
            baseb[qq][k] = d << 7;
            swzb[qq][k]  = fswz(d) << 3;
        }
    }

    // ---- staging mapping: thread -> (group g, col-pair np) ----
    const int g  = tid >> 4;     // 0..63
    const int np = tid & 15;     // 0..15 (2 cols each)
    const int ncol0 = bid * (NSUB * SUBW);   // 256 cols per block

    float acc0 = 0.f, acc1 = 0.f;
    float2 eA[BIN], eB[BIN];

    // prologue: 2 subtiles in flight
    issue_loads(W, eA, g, np, ncol0 + 0 * SUBW);
    issue_loads(W, eB, g, np, ncol0 + 1 * SUBW);

#pragma unroll
    for (int m = 0; m < NMAC; ++m) {
        // ---- normalize both halves of macro m; re-issue into freed buffers ----
        normalize_store(smem, eA, g, np, 0);
        if (2 * m + 2 < NSUB) issue_loads(W, eA, g, np, ncol0 + (2 * m + 2) * SUBW);
        __builtin_amdgcn_sched_barrier(0);
        normalize_store(smem, eB, g, np, 1);
        if (2 * m + 3 < NSUB) issue_loads(W, eB, g, np, ncol0 + (2 * m + 3) * SUBW);
        __builtin_amdgcn_sched_barrier(0);
        __syncthreads();

        // ---- compute: 2 queries, 16 qword-iterations (4 cols each) ----
#pragma unroll
        for (int j = 0; j < 16; ++j) {
            const int j8 = j << 3;
            const uint2 va0 = *(const uint2*)(smem + baseb[0][0] + (j8 ^ swzb[0][0]));
            const uint2 vb0 = *(const uint2*)(smem + baseb[0][1] + (j8 ^ swzb[0][1]));
            const uint2 vc0 = *(const uint2*)(smem + baseb[0][2] + (j8 ^ swzb[0][2]));
            const uint2 va1 = *(const uint2*)(smem + baseb[1][0] + (j8 ^ swzb[1][0]));
            const uint2 vb1 = *(const uint2*)(smem + baseb[1][1] + (j8 ^ swzb[1][1]));
            const uint2 vc1 = *(const uint2*)(smem + baseb[1][2] + (j8 ^ swzb[1][2]));
            {
                const float a0 = __uint_as_float(va0.x << 16), a1 = __uint_as_float(va0.x & 0xffff0000u);
                const float a2 = __uint_as_float(va0.y << 16), a3 = __uint_as_float(va0.y & 0xffff0000u);
                const float b0 = __uint_as_float(vb0.x << 16), b1 = __uint_as_float(vb0.x & 0xffff0000u);
                const float b2 = __uint_as_float(vb0.y << 16), b3 = __uint_as_float(vb0.y & 0xffff0000u);
                const float c0 = __uint_as_float(vc0.x << 16), c1 = __uint_as_float(vc0.x & 0xffff0000u);
                const float c2 = __uint_as_float(vc0.y << 16), c3 = __uint_as_float(vc0.y & 0xffff0000u);
                acc0 = fmaf(a0 * b0, c0, acc0);
                acc0 = fmaf(a1 * b1, c1, acc0);
                acc0 = fmaf(a2 * b2, c2, acc0);
                acc0 = fmaf(a3 * b3, c3, acc0);
            }
            {
                const float a0 = __uint_as_float(va1.x << 16), a1 = __uint_as_float(va1.x & 0xffff0000u);
                const float a2 = __uint_as_float(va1.y << 16), a3 = __uint_as_float(va1.y & 0xffff0000u);
                const float b0 = __uint_as_float(vb1.x << 16), b1 = __uint_as_float(vb1.x & 0xffff0000u);
                const float b2 = __uint_as_float(vb1.y << 16), b3 = __uint_as_float(vb1.y & 0xffff0000u);
                const float c0 = __uint_as_float(vc1.x << 16), c1 = __uint_as_float(vc1.x & 0xffff0000u);
                const float c2 = __uint_as_float(vc1.y << 16), c3 = __uint_as_float(vc1.y & 0xffff0000u);
                acc1 = fmaf(a0 * b0, c0, acc1);
                acc1 = fmaf(a1 * b1, c1, acc1);
                acc1 = fmaf(a2 * b2, c2, acc1);
                acc1 = fmaf(a3 * b3, c3, acc1);
            }
        }
        __syncthreads();
    }

    if (ATOMIC) {
        atomicAdd(outp + q0,     acc0 * (1.0f / N_DIM));
        atomicAdd(outp + q0 + 1, acc1 * (1.0f / N_DIM));
    } else {
        outp[(size_t)bid * Q_DIM + q0]     = acc0;
        outp[(size_t)bid * Q_DIM + q0 + 1] = acc1;
    }
}

__global__ __launch_bounds__(256) void rap_reduce(const float* __restrict__ partials,
                                                  float* __restrict__ outp) {
    const int q = blockIdx.x * blockDim.x + threadIdx.x;
    float s0 = 0.f, s1 = 0.f, s2 = 0.f, s3 = 0.f;
#pragma unroll 4
    for (int b = 0; b < NBLK; b += 4) {
        s0 += partials[(size_t)(b + 0) * Q_DIM + q];
        s1 += partials[(size_t)(b + 1) * Q_DIM + q];
        s2 += partials[(size_t)(b + 2) * Q_DIM + q];
        s3 += partials[(size_t)(b + 3) * Q_DIM + q];
    }
    outp[q] = ((s0 + s1) + (s2 + s3)) * (1.0f / N_DIM);
}

extern "C" void kernel_launch(void* const* d_in, const int* in_sizes, int n_in,
                              void* d_out, int out_size, void* d_ws, size_t ws_size,
                              hipStream_t stream) {
    const float* W    = (const float*)d_in[0];
    const int*   qidx = (const int*)d_in[1];
    float*       outp = (float*)d_out;

    const size_t need = (size_t)NBLK * Q_DIM * sizeof(float);
    if (ws_size >= need) {
        (void)hipFuncSetAttribute((const void*)rap_main<false>,
                                  hipFuncAttributeMaxDynamicSharedMemorySize, LDS_BYTES);
        float* partials = (float*)d_ws;
        hipLaunchKernelGGL(rap_main<false>, dim3(NBLK), dim3(TPB), LDS_BYTES, stream,
                           W, qidx, partials);
        hipLaunchKernelGGL(rap_reduce, dim3(Q_DIM / 256), dim3(256), 0, stream,
                           partials, outp);
    } else {
        (void)hipFuncSetAttribute((const void*)rap_main<true>,
                                  hipFuncAttributeMaxDynamicSharedMemorySize, LDS_BYTES);
        (void)hipMemsetAsync(d_out, 0, Q_DIM * sizeof(float), stream);
        hipLaunchKernelGGL(rap_main<true>, dim3(NBLK), dim3(TPB), LDS_BYTES, stream,
                           W, qidx, outp);
    }
}

// Round 4
// 169.912 us; speedup vs baseline: 2.1221x; 2.1221x over previous
//
#include <hip/hip_runtime.h>
#include <stdint.h>

#define D_DIM 1024
#define N_DIM 65536
#define BIN   16
#define Q_DIM 2048
#define K_DIM 3

#define NBLK  256            // one block per CU
#define TPB   1024
#define CHW   8              // cols per chunk
#define NCH   32             // chunks per block -> 256 cols
#define MACW  32             // cols per macro (4 chunks)
#define NMAC  8

// LDS map (dynamic):
#define RAW_OFF   0          // 2 x 32768 B raw f32 [1024 rows][8 cols], dbuf
#define SUMS_OFF  65536      // 64 groups x 8 cols x f32 reciprocals = 2048 B
#define TAB_OFF   67584      // bf16 table [1024 rows][32 cols] = 65536 B, granule-swizzled
#define LDS_TOTAL 133120

#define VMCNT2() asm volatile("s_waitcnt vmcnt(2)" ::: "memory")
#define VMCNT0() asm volatile("s_waitcnt vmcnt(0)" ::: "memory")
#define LGKM0()  asm volatile("s_waitcnt lgkmcnt(0)" ::: "memory")
#define SCHED0() __builtin_amdgcn_sched_barrier(0)
#define SBAR()   __builtin_amdgcn_s_barrier()

typedef const __attribute__((address_space(1))) uint32_t  glb_u32;
typedef __attribute__((address_space(3))) uint32_t        lds_u32;

// round-to-nearest-even f32 -> bf16 (positive normal probs)
__device__ __forceinline__ uint32_t f2bf(float f) {
    uint32_t u = __float_as_uint(f);
    return (u + 0x7fffu + ((u >> 16) & 1u)) >> 16;
}
__device__ __forceinline__ float blo(uint32_t u) { return __uint_as_float(u << 16); }
__device__ __forceinline__ float bhi(uint32_t u) { return __uint_as_float(u & 0xffff0000u); }

// DMA one 8-col chunk (32 KB) into raw slot (c&1). Wave w stages rows
// [w*64, w*64+64): 2 insts x (32 rows x 32 B). LDS dest is wave-uniform
// base + lane*16 (linear); the 4-col granule position within each row is
// bank-swizzled by pre-swizzling the per-lane GLOBAL column (key (r>>2)&1).
__device__ __forceinline__ void stage_chunk(const float* __restrict__ W, char* smem,
                                            int c, int col0, int w, int l) {
    const int slot = ((c & 1) << 15) + (w << 11);
    const int r0 = (w << 6) + (l >> 1);
    const int r1 = r0 + 32;
    const float* g0 = W + ((size_t)r0 << 16) + (col0 + (((l & 1) ^ ((r0 >> 2) & 1)) << 2));
    const float* g1 = W + ((size_t)r1 << 16) + (col0 + (((l & 1) ^ ((r1 >> 2) & 1)) << 2));
    __builtin_amdgcn_global_load_lds((glb_u32*)g0, (lds_u32*)(smem + slot),        16, 0, 0);
    __builtin_amdgcn_global_load_lds((glb_u32*)g1, (lds_u32*)(smem + slot + 1024), 16, 0, 0);
}

template<bool ATOMIC>
__global__ __launch_bounds__(TPB, 4) void rap_main(const float* __restrict__ W,
                                                   const int* __restrict__ qidx,
                                                   float* __restrict__ outp) {
    extern __shared__ char smem[];
    const int tid = threadIdx.x;
    const int bid = blockIdx.x;
    const int w = tid >> 6, l = tid & 63;

    // ---- per-thread query constants (2 queries/thread) ----
    const int q0 = tid * 2;
    int baseb[2][K_DIM];   // d*64 : byte base of table row
    int swzb[2][K_DIM];    // ((d>>1)&3)<<4 : granule XOR key in bytes
#pragma unroll
    for (int qq = 0; qq < 2; ++qq) {
#pragma unroll
        for (int k = 0; k < K_DIM; ++k) {
            const int d = qidx[(q0 + qq) * K_DIM + k];
            baseb[qq][k] = d << 6;
            swzb[qq][k]  = ((d >> 1) & 3) << 4;
        }
    }

    // pass-1 mapping: thread -> (group, col, bin-half)
    const int g1g = tid >> 4;          // 0..63
    const int p1c = (tid >> 1) & 7;    // 0..7
    const int p1h = tid & 1;           // 0..1
    const int ncol0 = bid * (NCH * CHW);

    float acc0 = 0.f, acc1 = 0.f;

    // drain setup loads so vmcnt counts only stage DMAs
    VMCNT0(); SCHED0();
    stage_chunk(W, smem, 0, ncol0 + 0 * CHW, w, l);
    stage_chunk(W, smem, 1, ncol0 + 1 * CHW, w, l);

    for (int m = 0; m < NMAC; ++m) {
#pragma unroll
        for (int s = 0; s < 4; ++s) {
            const int c = m * 4 + s;
            if (c == NCH - 1) { VMCNT0(); } else { VMCNT2(); }
            SCHED0();
            const int slot = (c & 1) << 15;

            // ---- pass 1: reciprocal of softmax denominators ----
            {
                float sum = 0.f;
                const int rbase = g1g * 16 + p1h * 8;
#pragma unroll
                for (int j = 0; j < 8; ++j) {
                    const int gran = (p1c >> 2) ^ ((j >> 2) & 1);
                    const float v = *(const float*)(smem + slot + (rbase + j) * 32
                                                    + gran * 16 + (p1c & 3) * 4);
                    sum += __expf(v);
                }
                sum += __shfl_xor(sum, 1);
                const float rec = __builtin_amdgcn_rcpf(sum);
                if (p1h == 0)
                    *(float*)(smem + SUMS_OFF + g1g * 32 + p1c * 4) = rec;
            }
            LGKM0(); SCHED0();

            // ---- pass 2: normalize own row, pack bf16, write table granule s ----
            {
                const int r = tid;
                const int key = (r >> 2) & 1;
                const uint4 rawA = *(const uint4*)(smem + slot + r * 32 + (key << 4));        // cols 0..3
                const uint4 rawB = *(const uint4*)(smem + slot + r * 32 + ((key ^ 1) << 4));  // cols 4..7
                const int g2 = r >> 4;
                const float4 rc0 = *(const float4*)(smem + SUMS_OFF + g2 * 32);
                const float4 rc1 = *(const float4*)(smem + SUMS_OFF + g2 * 32 + 16);
                const float* fA = (const float*)&rawA;
                const float* fB = (const float*)&rawB;
                uint4 pk;
                pk.x = f2bf(__expf(fA[0]) * rc0.x) | (f2bf(__expf(fA[1]) * rc0.y) << 16);
                pk.y = f2bf(__expf(fA[2]) * rc0.z) | (f2bf(__expf(fA[3]) * rc0.w) << 16);
                pk.z = f2bf(__expf(fB[0]) * rc1.x) | (f2bf(__expf(fB[1]) * rc1.y) << 16);
                pk.w = f2bf(__expf(fB[2]) * rc1.z) | (f2bf(__expf(fB[3]) * rc1.w) << 16);
                const int gphys = s ^ ((r >> 1) & 3);
                *(uint4*)(smem + TAB_OFF + r * 64 + (gphys << 4)) = pk;
            }
            LGKM0(); SCHED0();   // raw-slot reads retired -> safe to re-fill

            if (c < NCH - 2)
                stage_chunk(W, smem, c + 2, ncol0 + (c + 2) * CHW, w, l);
        }

        LGKM0(); SCHED0(); SBAR(); SCHED0();   // table published

        // ---- compute: 2 queries x 4 granules x 8 cols ----
#pragma unroll
        for (int g16 = 0; g16 < 4; ++g16) {
            const int gb = g16 << 4;
            {
                const uint4 va = *(const uint4*)(smem + TAB_OFF + baseb[0][0] + (gb ^ swzb[0][0]));
                const uint4 vb = *(const uint4*)(smem + TAB_OFF + baseb[0][1] + (gb ^ swzb[0][1]));
                const uint4 vc = *(const uint4*)(smem + TAB_OFF + baseb[0][2] + (gb ^ swzb[0][2]));
                acc0 = fmaf(blo(va.x) * blo(vb.x), blo(vc.x), acc0);
                acc0 = fmaf(bhi(va.x) * bhi(vb.x), bhi(vc.x), acc0);
                acc0 = fmaf(blo(va.y) * blo(vb.y), blo(vc.y), acc0);
                acc0 = fmaf(bhi(va.y) * bhi(vb.y), bhi(vc.y), acc0);
                acc0 = fmaf(blo(va.z) * blo(vb.z), blo(vc.z), acc0);
                acc0 = fmaf(bhi(va.z) * bhi(vb.z), bhi(vc.z), acc0);
                acc0 = fmaf(blo(va.w) * blo(vb.w), blo(vc.w), acc0);
                acc0 = fmaf(bhi(va.w) * bhi(vb.w), bhi(vc.w), acc0);
            }
            {
                const uint4 va = *(const uint4*)(smem + TAB_OFF + baseb[1][0] + (gb ^ swzb[1][0]));
                const uint4 vb = *(const uint4*)(smem + TAB_OFF + baseb[1][1] + (gb ^ swzb[1][1]));
                const uint4 vc = *(const uint4*)(smem + TAB_OFF + baseb[1][2] + (gb ^ swzb[1][2]));
                acc1 = fmaf(blo(va.x) * blo(vb.x), blo(vc.x), acc1);
                acc1 = fmaf(bhi(va.x) * bhi(vb.x), bhi(vc.x), acc1);
                acc1 = fmaf(blo(va.y) * blo(vb.y), blo(vc.y), acc1);
                acc1 = fmaf(bhi(va.y) * bhi(vb.y), bhi(vc.y), acc1);
                acc1 = fmaf(blo(va.z) * blo(vb.z), blo(vc.z), acc1);
                acc1 = fmaf(bhi(va.z) * bhi(vb.z), bhi(vc.z), acc1);
                acc1 = fmaf(blo(va.w) * blo(vb.w), blo(vc.w), acc1);
                acc1 = fmaf(bhi(va.w) * bhi(vb.w), bhi(vc.w), acc1);
            }
        }

        LGKM0(); SCHED0(); SBAR(); SCHED0();   // table consumed -> free for next macro
    }

    if (ATOMIC) {
        atomicAdd(outp + q0,     acc0 * (1.0f / N_DIM));
        atomicAdd(outp + q0 + 1, acc1 * (1.0f / N_DIM));
    } else {
        outp[(size_t)bid * Q_DIM + q0]     = acc0;
        outp[(size_t)bid * Q_DIM + q0 + 1] = acc1;
    }
}

__global__ __launch_bounds__(256) void rap_reduce(const float* __restrict__ partials,
                                                  float* __restrict__ outp) {
    const int q = blockIdx.x * blockDim.x + threadIdx.x;
    float s0 = 0.f, s1 = 0.f, s2 = 0.f, s3 = 0.f;
#pragma unroll 4
    for (int b = 0; b < NBLK; b += 4) {
        s0 += partials[(size_t)(b + 0) * Q_DIM + q];
        s1 += partials[(size_t)(b + 1) * Q_DIM + q];
        s2 += partials[(size_t)(b + 2) * Q_DIM + q];
        s3 += partials[(size_t)(b + 3) * Q_DIM + q];
    }
    outp[q] = ((s0 + s1) + (s2 + s3)) * (1.0f / N_DIM);
}

extern "C" void kernel_launch(void* const* d_in, const int* in_sizes, int n_in,
                              void* d_out, int out_size, void* d_ws, size_t ws_size,
                              hipStream_t stream) {
    const float* W    = (const float*)d_in[0];
    const int*   qidx = (const int*)d_in[1];
    float*       outp = (float*)d_out;

    const size_t need = (size_t)NBLK * Q_DIM * sizeof(float);
    if (ws_size >= need) {
        (void)hipFuncSetAttribute((const void*)rap_main<false>,
                                  hipFuncAttributeMaxDynamicSharedMemorySize, LDS_TOTAL);
        float* partials = (float*)d_ws;
        hipLaunchKernelGGL(rap_main<false>, dim3(NBLK), dim3(TPB), LDS_TOTAL, stream,
                           W, qidx, partials);
        hipLaunchKernelGGL(rap_reduce, dim3(Q_DIM / 256), dim3(256), 0, stream,
                           partials, outp);
    } else {
        (void)hipFuncSetAttribute((const void*)rap_main<true>,
                                  hipFuncAttributeMaxDynamicSharedMemorySize, LDS_TOTAL);
        (void)hipMemsetAsync(d_out, 0, Q_DIM * sizeof(float), stream);
        hipLaunchKernelGGL(rap_main<true>, dim3(NBLK), dim3(TPB), LDS_TOTAL, stream,
                           W, qidx, outp);
    }
}

// Round 5
// 90.684 us; speedup vs baseline: 3.9761x; 1.8737x over previous
//
#include <hip/hip_runtime.h>
#include <stdint.h>

#define D_DIM 1024
#define N_DIM 65536
#define Q_DIM 2048
#define K_DIM 3

#define NBLK  256            // one block per CU
#define TPB   1024           // 16 waves
#define MACW  32             // cols per macro (compute granularity)
#define NMAC  8              // macros per block -> 256 cols
#define NQT   32             // total stage-quarters (NMAC * 4)
#define QROWS 256            // rows per quarter (one quarter = 256 rows x 128 B = 32 KB)

// LDS map (dynamic):
#define RAW_OFF   0          // 2 x 32768 B raw f32 quarter buffers (dbuf)
#define SUMS_OFF  65536      // 16 groups x 32 cols f32 reciprocals = 2048 B (per wave slice)
#define TAB_OFF   67584      // bf16 table [1024 rows][32 cols] = 65536 B, granule-swizzled
#define LDS_TOTAL 133120

#define VMCNT2() asm volatile("s_waitcnt vmcnt(2)" ::: "memory")
#define VMCNT0() asm volatile("s_waitcnt vmcnt(0)" ::: "memory")
#define LGKM0()  asm volatile("s_waitcnt lgkmcnt(0)" ::: "memory")
#define SCHED0() __builtin_amdgcn_sched_barrier(0)
#define SBAR()   __builtin_amdgcn_s_barrier()

typedef const __attribute__((address_space(1))) uint32_t  glb_u32;
typedef __attribute__((address_space(3))) uint32_t        lds_u32;

// round-to-nearest-even f32 -> bf16 (positive normal probs)
__device__ __forceinline__ uint32_t f2bf(float f) {
    uint32_t u = __float_as_uint(f);
    return (u + 0x7fffu + ((u >> 16) & 1u)) >> 16;
}
__device__ __forceinline__ float blo(uint32_t u) { return __uint_as_float(u << 16); }
__device__ __forceinline__ float bhi(uint32_t u) { return __uint_as_float(u & 0xffff0000u); }

// DMA one quarter (256 rows x 128 B) into raw slot (c&1). Wave w stages rows
// [w*16, w*16+16): 2 insts x (8 rows x full 128-B row span) -> every HBM line
// fetched exactly once, fully. Raw buffer is XOR-swizzled (16-B granule key
// r&7) by pre-swizzling the per-lane GLOBAL column; LDS dest stays linear
// (wave-uniform base + lane*16).
__device__ __forceinline__ void stage_quarter(const float* __restrict__ W, char* smem,
                                              int c, int bid, int w, int l) {
    const int slot  = (c & 1) << 15;
    const int col0  = bid * (NMAC * MACW) + (c >> 2) * MACW;
    const int gsrc  = ((l & 7) ^ ((l >> 3) & 7)) << 2;         // swizzled col offset (floats)
    const int d0    = (c & 3) * QROWS + w * 16 + (l >> 3);     // global row, inst 0
    const float* g0 = W + ((size_t)d0 << 16) + col0 + gsrc;
    const float* g1 = W + ((size_t)(d0 + 8) << 16) + col0 + gsrc;
    __builtin_amdgcn_global_load_lds((glb_u32*)g0, (lds_u32*)(smem + slot + w * 2048),        16, 0, 0);
    __builtin_amdgcn_global_load_lds((glb_u32*)g1, (lds_u32*)(smem + slot + w * 2048 + 1024), 16, 0, 0);
}

template<bool ATOMIC>
__global__ __launch_bounds__(TPB, 4) void rap_main(const float* __restrict__ W,
                                                   const int* __restrict__ qidx,
                                                   float* __restrict__ outp) {
    extern __shared__ char smem[];
    const int tid = threadIdx.x;
    const int bid = blockIdx.x;
    const int w = tid >> 6, l = tid & 63;

    // ---- per-thread query constants (2 queries/thread) ----
    const int q0 = tid * 2;
    int baseb[2][K_DIM];   // d*64 : byte base of table row
    int swzb[2][K_DIM];    // ((d>>1)&3)<<4 : granule XOR key in bytes
#pragma unroll
    for (int qq = 0; qq < 2; ++qq) {
#pragma unroll
        for (int k = 0; k < K_DIM; ++k) {
            const int d = qidx[(q0 + qq) * K_DIM + k];
            baseb[qq][k] = d << 6;
            swzb[qq][k]  = ((d >> 1) & 3) << 4;
        }
    }

    // pass-1 mapping: lane -> (col, bin-half) within wave w's 16-row group
    const int c_col = l >> 1;          // 0..31
    const int h     = l & 1;           // 0..1
    // pass-2 mapping: lane -> (row within wave slice, granule pair)
    const int rr2 = w * 16 + (l >> 2); // quarter-local row 0..255
    const int gp  = l & 3;             // 8-col pair -> table granule

    float acc0 = 0.f, acc1 = 0.f;

    // drain setup loads so vmcnt counts only stage DMAs
    VMCNT0(); SCHED0();
    stage_quarter(W, smem, 0, bid, w, l);
    stage_quarter(W, smem, 1, bid, w, l);

    for (int m = 0; m < NMAC; ++m) {
#pragma unroll
        for (int s = 0; s < 4; ++s) {
            const int c = m * 4 + s;
            if (c == NQT - 1) { VMCNT0(); } else { VMCNT2(); }
            SCHED0();
            const int slot = (c & 1) << 15;

            // ---- pass 1: reciprocal softmax denominators (wave-local group w) ----
            {
                float sum = 0.f;
#pragma unroll
                for (int j = 0; j < 8; ++j) {
                    const float v = *(const float*)(smem + slot + (w * 16 + h * 8 + j) * 128
                                                    + (((c_col >> 2) ^ j) << 4) + (c_col & 3) * 4);
                    sum += __expf(v);
                }
                sum += __shfl_xor(sum, 1);
                const float rec = __builtin_amdgcn_rcpf(sum);
                if (h == 0)
                    *(float*)(smem + SUMS_OFF + w * 128 + c_col * 4) = rec;
            }
            LGKM0(); SCHED0();

            // ---- pass 2: read own row span + recs ----
            const int pg0 = (2 * gp) ^ (rr2 & 7);
            const uint4 rawA = *(const uint4*)(smem + slot + rr2 * 128 + (pg0 << 4));
            const uint4 rawB = *(const uint4*)(smem + slot + rr2 * 128 + ((pg0 ^ 1) << 4));
            const float4 rc0 = *(const float4*)(smem + SUMS_OFF + w * 128 + gp * 32);
            const float4 rc1 = *(const float4*)(smem + SUMS_OFF + w * 128 + gp * 32 + 16);
            LGKM0(); SCHED0();

            // raw slot fully consumed by this wave -> refill it early
            if (c + 2 < NQT) stage_quarter(W, smem, c + 2, bid, w, l);
            SCHED0();

            // ---- pass 2: normalize, pack bf16, write table ----
            {
                const float* fA = (const float*)&rawA;
                const float* fB = (const float*)&rawB;
                uint4 pk;
                pk.x = f2bf(__expf(fA[0]) * rc0.x) | (f2bf(__expf(fA[1]) * rc0.y) << 16);
                pk.y = f2bf(__expf(fA[2]) * rc0.z) | (f2bf(__expf(fA[3]) * rc0.w) << 16);
                pk.z = f2bf(__expf(fB[0]) * rc1.x) | (f2bf(__expf(fB[1]) * rc1.y) << 16);
                pk.w = f2bf(__expf(fB[2]) * rc1.z) | (f2bf(__expf(fB[3]) * rc1.w) << 16);
                const int row_d = (c & 3) * QROWS + rr2;
                *(uint4*)(smem + TAB_OFF + row_d * 64 + ((gp ^ ((row_d >> 1) & 3)) << 4)) = pk;
            }
        }

        LGKM0(); SCHED0(); SBAR(); SCHED0();   // table published

        // ---- compute: 2 queries x 4 granules x 8 cols ----
#pragma unroll
        for (int g16 = 0; g16 < 4; ++g16) {
            const int gb = g16 << 4;
            {
                const uint4 va = *(const uint4*)(smem + TAB_OFF + baseb[0][0] + (gb ^ swzb[0][0]));
                const uint4 vb = *(const uint4*)(smem + TAB_OFF + baseb[0][1] + (gb ^ swzb[0][1]));
                const uint4 vc = *(const uint4*)(smem + TAB_OFF + baseb[0][2] + (gb ^ swzb[0][2]));
                acc0 = fmaf(blo(va.x) * blo(vb.x), blo(vc.x), acc0);
                acc0 = fmaf(bhi(va.x) * bhi(vb.x), bhi(vc.x), acc0);
                acc0 = fmaf(blo(va.y) * blo(vb.y), blo(vc.y), acc0);
                acc0 = fmaf(bhi(va.y) * bhi(vb.y), bhi(vc.y), acc0);
                acc0 = fmaf(blo(va.z) * blo(vb.z), blo(vc.z), acc0);
                acc0 = fmaf(bhi(va.z) * bhi(vb.z), bhi(vc.z), acc0);
                acc0 = fmaf(blo(va.w) * blo(vb.w), blo(vc.w), acc0);
                acc0 = fmaf(bhi(va.w) * bhi(vb.w), bhi(vc.w), acc0);
            }
            {
                const uint4 va = *(const uint4*)(smem + TAB_OFF + baseb[1][0] + (gb ^ swzb[1][0]));
                const uint4 vb = *(const uint4*)(smem + TAB_OFF + baseb[1][1] + (gb ^ swzb[1][1]));
                const uint4 vc = *(const uint4*)(smem + TAB_OFF + baseb[1][2] + (gb ^ swzb[1][2]));
                acc1 = fmaf(blo(va.x) * blo(vb.x), blo(vc.x), acc1);
                acc1 = fmaf(bhi(va.x) * bhi(vb.x), bhi(vc.x), acc1);
                acc1 = fmaf(blo(va.y) * blo(vb.y), blo(vc.y), acc1);
                acc1 = fmaf(bhi(va.y) * bhi(vb.y), bhi(vc.y), acc1);
                acc1 = fmaf(blo(va.z) * blo(vb.z), blo(vc.z), acc1);
                acc1 = fmaf(bhi(va.z) * bhi(vb.z), bhi(vc.z), acc1);
                acc1 = fmaf(blo(va.w) * blo(vb.w), blo(vc.w), acc1);
                acc1 = fmaf(bhi(va.w) * bhi(vb.w), bhi(vc.w), acc1);
            }
        }

        LGKM0(); SCHED0(); SBAR(); SCHED0();   // table consumed -> free for next macro
    }

    if (ATOMIC) {
        atomicAdd(outp + q0,     acc0 * (1.0f / N_DIM));
        atomicAdd(outp + q0 + 1, acc1 * (1.0f / N_DIM));
    } else {
        outp[(size_t)bid * Q_DIM + q0]     = acc0;
        outp[(size_t)bid * Q_DIM + q0 + 1] = acc1;
    }
}

__global__ __launch_bounds__(256) void rap_reduce(const float* __restrict__ partials,
                                                  float* __restrict__ outp) {
    const int q = blockIdx.x * blockDim.x + threadIdx.x;
    float s0 = 0.f, s1 = 0.f, s2 = 0.f, s3 = 0.f;
#pragma unroll 4
    for (int b = 0; b < NBLK; b += 4) {
        s0 += partials[(size_t)(b + 0) * Q_DIM + q];
        s1 += partials[(size_t)(b + 1) * Q_DIM + q];
        s2 += partials[(size_t)(b + 2) * Q_DIM + q];
        s3 += partials[(size_t)(b + 3) * Q_DIM + q];
    }
    outp[q] = ((s0 + s1) + (s2 + s3)) * (1.0f / N_DIM);
}

extern "C" void kernel_launch(void* const* d_in, const int* in_sizes, int n_in,
                              void* d_out, int out_size, void* d_ws, size_t ws_size,
                              hipStream_t stream) {
    const float* W    = (const float*)d_in[0];
    const int*   qidx = (const int*)d_in[1];
    float*       outp = (float*)d_out;

    const size_t need = (size_t)NBLK * Q_DIM * sizeof(float);
    if (ws_size >= need) {
        (void)hipFuncSetAttribute((const void*)rap_main<false>,
                                  hipFuncAttributeMaxDynamicSharedMemorySize, LDS_TOTAL);
        float* partials = (float*)d_ws;
        hipLaunchKernelGGL(rap_main<false>, dim3(NBLK), dim3(TPB), LDS_TOTAL, stream,
                           W, qidx, partials);
        hipLaunchKernelGGL(rap_reduce, dim3(Q_DIM / 256), dim3(256), 0, stream,
                           partials, outp);
    } else {
        (void)hipFuncSetAttribute((const void*)rap_main<true>,
                                  hipFuncAttributeMaxDynamicSharedMemorySize, LDS_TOTAL);
        (void)hipMemsetAsync(d_out, 0, Q_DIM * sizeof(float), stream);
        hipLaunchKernelGGL(rap_main<true>, dim3(NBLK), dim3(TPB), LDS_TOTAL, stream,
                           W, qidx, outp);
    }
}